// Round 4
// baseline (335.694 us; speedup 1.0000x reference)
//
#include <hip/hip_runtime.h>
#include <hip/hip_bf16.h>
#include <math.h>

typedef __bf16 bf16x8 __attribute__((ext_vector_type(8)));
typedef float floatx4 __attribute__((ext_vector_type(4)));

#define ATT_SCALE 0.35355339059327373f  // DH^-0.5, DH=8

__device__ __forceinline__ __bf16 f2b(float x) { return (__bf16)x; }

// ---------------------------------------------------------------------------
// K1: Q = p@wq, Ks = (p@wk)*SCALE, V = p@wv  (rows 0..2047), q1 = queries@cq_wq
// grid 2304 x 64
// ---------------------------------------------------------------------------
__global__ void k_proj(const float* __restrict__ p, const float* __restrict__ quer,
                       const float* __restrict__ wq, const float* __restrict__ wk,
                       const float* __restrict__ wv, const float* __restrict__ cq_wq,
                       float* __restrict__ Q, float* __restrict__ Ks,
                       float* __restrict__ V, float* __restrict__ q1) {
  int blk = blockIdx.x, t = threadIdx.x;
  __shared__ float xr[64];
  if (blk < 2048) {
    xr[t] = p[blk * 64 + t];
    __syncthreads();
    float aq = 0.f, ak = 0.f, av = 0.f;
    for (int c = 0; c < 64; c++) {
      float x = xr[c];
      aq += x * wq[c * 64 + t];
      ak += x * wk[c * 64 + t];
      av += x * wv[c * 64 + t];
    }
    Q[blk * 64 + t] = aq;
    Ks[blk * 64 + t] = ak * ATT_SCALE;
    V[blk * 64 + t] = av;
  } else {
    int r = blk - 2048;  // 0..255 query rows
    xr[t] = quer[r * 64 + t];
    __syncthreads();
    float a = 0.f;
    for (int c = 0; c < 64; c++) a += xr[c] * cq_wq[c * 64 + t];
    q1[r * 64 + t] = a;
  }
}

// ---------------------------------------------------------------------------
// K2 v5: edge attention, transposed MFMA, depth-2 e prefetch, correct vmcnt
// age ordering (L2 loads issued BEFORE the HBM prefetch each step, so waits
// on L2 values never drain the prefetch). No launch_bounds -> no spills.
// grid 2048 x 256 (wave w owns j in [w*64, w*64+64))
// ---------------------------------------------------------------------------
#define LOADT(ER, JT) do {                         \
    const float* _np = ebase + (JT) * 1024;        \
    ER[0] = *(const float4*)(_np);                 \
    ER[1] = *(const float4*)(_np + 4);             \
    ER[2] = *(const float4*)(_np + 32);            \
    ER[3] = *(const float4*)(_np + 36);            \
  } while (0)

#define NTCOMP(NT, KF, VA) do {                                               \
    floatx4 acc = {0.f, 0.f, 0.f, 0.f};                                       \
    acc = __builtin_amdgcn_mfma_f32_16x16x32_bf16(wfrag[NT][0], a0, acc, 0, 0, 0); \
    acc = __builtin_amdgcn_mfma_f32_16x16x32_bf16(wfrag[NT][1], a1, acc, 0, 0, 0); \
    float s = acc[0] * KF.x * qv[NT].x + acc[1] * KF.y * qv[NT].y +           \
              acc[2] * KF.z * qv[NT].z + acc[3] * KF.w * qv[NT].w;            \
    s += __shfl_xor(s, 16);                                                   \
    float wg = __expf(s) * kwm;                                               \
    aden[NT] += wg;                                                           \
    aout[NT][0] += wg * VA.x; aout[NT][1] += wg * VA.y;                       \
    aout[NT][2] += wg * VA.z; aout[NT][3] += wg * VA.w;                       \
  } while (0)

#define STEP(JT, ER, PFSTMT) do {                                             \
    int jS = w * 64 + (JT) * 16 + l15;                                        \
    const float* ksrow = Ks + ((long)(b * 256 + jS)) * 64 + quad * 4;         \
    const float* vrow  = V  + ((long)(b * 256 + jS)) * 64 + hsel * 8 + par * 4; \
    float4 kf0 = *(const float4*)(ksrow);                                     \
    float4 kf1 = *(const float4*)(ksrow + 16);                                \
    float4 kf2 = *(const float4*)(ksrow + 32);                                \
    float4 kf3 = *(const float4*)(ksrow + 48);                                \
    float4 va0 = *(const float4*)(vrow);                                      \
    float4 va1 = *(const float4*)(vrow + 16);                                 \
    float4 va2 = *(const float4*)(vrow + 32);                                 \
    float4 va3 = *(const float4*)(vrow + 48);                                 \
    float kwm = krw[(long)bi * 256 + jS] * mask[b * 256 + jS];                \
    __builtin_amdgcn_sched_barrier(0);                                        \
    PFSTMT;                                                                   \
    __builtin_amdgcn_sched_barrier(0);                                        \
    bf16x8 a0, a1;                                                            \
    a0[0] = f2b(ER[0].x); a0[1] = f2b(ER[0].y);                               \
    a0[2] = f2b(ER[0].z); a0[3] = f2b(ER[0].w);                               \
    a0[4] = f2b(ER[1].x); a0[5] = f2b(ER[1].y);                               \
    a0[6] = f2b(ER[1].z); a0[7] = f2b(ER[1].w);                               \
    a1[0] = f2b(ER[2].x); a1[1] = f2b(ER[2].y);                               \
    a1[2] = f2b(ER[2].z); a1[3] = f2b(ER[2].w);                               \
    a1[4] = f2b(ER[3].x); a1[5] = f2b(ER[3].y);                               \
    a1[6] = f2b(ER[3].z); a1[7] = f2b(ER[3].w);                               \
    NTCOMP(0, kf0, va0); NTCOMP(1, kf1, va1);                                 \
    NTCOMP(2, kf2, va2); NTCOMP(3, kf3, va3);                                 \
  } while (0)

__global__ void k_edge(
    const float* __restrict__ e, const float* __restrict__ we,
    const float* __restrict__ krw, const float* __restrict__ mask,
    const float* __restrict__ hin, const float* __restrict__ pin,
    const float* __restrict__ wo, const float* __restrict__ cq_wkv,
    const float* __restrict__ Q, const float* __restrict__ Ks,
    const float* __restrict__ V, float* __restrict__ Kc, float* __restrict__ Vc) {
  int bi = blockIdx.x;          // b*256 + i
  int b = bi >> 8;
  int t = threadIdx.x;
  int w = t >> 6, l = t & 63;
  int l15 = l & 15, quad = l >> 4;
  int hsel = quad >> 1;         // head offset within an nt pair (0 or 1)
  int par = quad & 1;           // dim-half this lane accumulates

  // we fragments (L2): lane holds we[c=kc*32+quad*8+jj][hk=nt*16+l15]
  bf16x8 wfrag[4][2];
#pragma unroll
  for (int nt = 0; nt < 4; nt++)
#pragma unroll
    for (int kc = 0; kc < 2; kc++)
#pragma unroll
      for (int jj = 0; jj < 8; jj++)
        wfrag[nt][kc][jj] = f2b(we[(kc * 32 + quad * 8 + jj) * 64 + nt * 16 + l15]);

  // qv is loop-invariant: Q[i][nt*16 + quad*4 .. +3]
  float4 qv[4];
#pragma unroll
  for (int nt = 0; nt < 4; nt++)
    qv[nt] = *(const float4*)(Q + bi * 64 + nt * 16 + quad * 4);

  float mi = mask[bi];

  float aout[4][4];
  float aden[4] = {0.f, 0.f, 0.f, 0.f};
#pragma unroll
  for (int nt = 0; nt < 4; nt++)
#pragma unroll
    for (int d = 0; d < 4; d++) aout[nt][d] = 0.f;

  const float* ebase = e + ((long)bi * 256 + w * 64 + l15) * 64 + quad * 8;

  float4 e0[4], e1[4], e2[4], e3[4];
  LOADT(e0, 0);
  LOADT(e1, 1);
  __builtin_amdgcn_sched_barrier(0);

  STEP(0, e0, LOADT(e2, 2));
  STEP(1, e1, LOADT(e3, 3));
  STEP(2, e2, (void)0);
  STEP(3, e3, (void)0);

  // reduce over the 16 j's per lane-group (l15)
#pragma unroll
  for (int nt = 0; nt < 4; nt++) {
    float dn = aden[nt];
    dn += __shfl_xor(dn, 1); dn += __shfl_xor(dn, 2);
    dn += __shfl_xor(dn, 4); dn += __shfl_xor(dn, 8);
    aden[nt] = dn;
#pragma unroll
    for (int d = 0; d < 4; d++) {
      float o = aout[nt][d];
      o += __shfl_xor(o, 1); o += __shfl_xor(o, 2);
      o += __shfl_xor(o, 4); o += __shfl_xor(o, 8);
      aout[nt][d] = o;
    }
  }

  __shared__ float red[4][64];
  __shared__ float redden[4][8];
  __shared__ float pav[64];
  __shared__ float hcl[64];
  if (l15 == 0) {               // lanes 0,16,32,48 of each wave
#pragma unroll
    for (int nt = 0; nt < 4; nt++) {
      int head = nt * 2 + hsel;
#pragma unroll
      for (int d = 0; d < 4; d++) red[w][head * 8 + par * 4 + d] = aout[nt][d];
      if (par == 0) redden[w][head] = aden[nt];
    }
  }
  __syncthreads();
  if (t < 64) {
    int head = t >> 3;
    float num = red[0][t] + red[1][t] + red[2][t] + red[3][t];
    float den = redden[0][head] + redden[1][head] + redden[2][head] + redden[3][head];
    num *= mi;
    den = fmaxf(den * mi, 1e-6f);
    pav[t] = num / den;  // p_attn[b,i,head*8+d]
  }
  __syncthreads();
  if (t < 64) {
    float a = 0.f;
    for (int c = 0; c < 64; c++) a += pav[c] * wo[c * 64 + t];
    hcl[t] = hin[bi * 64 + t] + pin[bi * 64 + t] + tanhf(a);
  }
  __syncthreads();
  if (t < 128) {
    float a = 0.f;
    for (int c = 0; c < 64; c++) a += hcl[c] * cq_wkv[c * 128 + t];
    if (t < 64) Kc[bi * 64 + t] = a;
    else        Vc[bi * 64 + t - 64] = a;
  }
}

// ---------------------------------------------------------------------------
// KA: cross-attn (4 latent rows per block, all heads) + q0 = quer + oc@cq_wo
//     + bo, then qq/kv projections for self-attn layer 0.
// grid 64 (b*8+rg) x 256. Row-local LDS only -> no barriers needed.
// ---------------------------------------------------------------------------
__global__ __launch_bounds__(256) void k_crossf(
    const float* __restrict__ q1, const float* __restrict__ Kc,
    const float* __restrict__ Vc, const float* __restrict__ mask,
    const float* __restrict__ quer, const float* __restrict__ cq_wo,
    const float* __restrict__ cq_bo, const float* __restrict__ wq0,
    const float* __restrict__ wkv0, float* __restrict__ q0g,
    float* __restrict__ qqg, float* __restrict__ kvg) {
  int blk = blockIdx.x, b = blk >> 3, rg = blk & 7;
  int t = threadIdx.x, rr = t >> 6, l = t & 63, h = l >> 3, g = l & 7;
  int gr = b * 32 + rg * 4 + rr;  // global latent row
  __shared__ float ocs[4][64];
  __shared__ float q0s[4][64];

  {
    const float* qp = q1 + gr * 64 + h * 8;
    float4 qa = *(const float4*)qp, qb = *(const float4*)(qp + 4);
    float num[8] = {0.f, 0.f, 0.f, 0.f, 0.f, 0.f, 0.f, 0.f};
    float den = 0.f;
#pragma unroll 4
    for (int jj = 0; jj < 32; jj++) {
      int j = jj * 8 + g;
      const float* kp = Kc + (b * 256 + j) * 64 + h * 8;
      float4 ka = *(const float4*)kp, kb = *(const float4*)(kp + 4);
      float s = qa.x * ka.x + qa.y * ka.y + qa.z * ka.z + qa.w * ka.w +
                qb.x * kb.x + qb.y * kb.y + qb.z * kb.z + qb.w * kb.w;
      s *= ATT_SCALE;
      float mj = mask[b * 256 + j];
      s = (mj > 0.5f) ? s : -1e30f;
      s = fminf(fmaxf(s, -5.f), 5.f);
      float ex = __expf(s);
      den += ex;
      const float* vp = Vc + (b * 256 + j) * 64 + h * 8;
      float4 va = *(const float4*)vp, vb = *(const float4*)(vp + 4);
      num[0] += ex * va.x; num[1] += ex * va.y;
      num[2] += ex * va.z; num[3] += ex * va.w;
      num[4] += ex * vb.x; num[5] += ex * vb.y;
      num[6] += ex * vb.z; num[7] += ex * vb.w;
    }
    den += __shfl_xor(den, 1); den += __shfl_xor(den, 2); den += __shfl_xor(den, 4);
#pragma unroll
    for (int d = 0; d < 8; d++) {
      float v = num[d];
      v += __shfl_xor(v, 1); v += __shfl_xor(v, 2); v += __shfl_xor(v, 4);
      num[d] = v;
    }
    float sel = num[0];
#pragma unroll
    for (int d = 1; d < 8; d++) sel = (g == d) ? num[d] : sel;
    ocs[rr][h * 8 + g] = sel / den;   // row-local: read only by this wave
  }

  int c = l;
  {
    float acc = quer[gr * 64 + c] + cq_bo[c];
    for (int k = 0; k < 64; k++) acc += ocs[rr][k] * cq_wo[k * 64 + c];
    q0g[gr * 64 + c] = acc;
    q0s[rr][c] = acc;
  }
  {
    float aq = 0.f, ak = 0.f, av = 0.f;
    for (int k = 0; k < 64; k++) {
      float x = q0s[rr][k];
      aq += x * wq0[k * 64 + c];
      ak += x * wkv0[k * 128 + c];
      av += x * wkv0[k * 128 + 64 + c];
    }
    qqg[gr * 64 + c] = aq;
    kvg[gr * 128 + c] = ak;
    kvg[gr * 128 + 64 + c] = av;
  }
}

// ---------------------------------------------------------------------------
// KB: latent self-attn (4 rows per block, K/V staged in LDS) + residual
//     projection + next layer's qq/kv projections.
// grid 64 x 256, one barrier (after K/V stage).
// ---------------------------------------------------------------------------
__global__ __launch_bounds__(256) void k_sattnf(
    const float* __restrict__ qq, const float* __restrict__ kv,
    const float* __restrict__ resid, const float* __restrict__ wo,
    const float* __restrict__ bo, const float* __restrict__ wq2,
    const float* __restrict__ wkv2, float* __restrict__ q_out,
    float* __restrict__ qq2, float* __restrict__ kv2) {
  int blk = blockIdx.x, b = blk >> 3, rg = blk & 7;
  int t = threadIdx.x, rr = t >> 6, l = t & 63, h = l >> 3, g = l & 7;
  int gr = b * 32 + rg * 4 + rr;
  __shared__ float KVs[32][128];
  __shared__ float ocs[4][64];
  __shared__ float q2s[4][64];

  const float4* s4 = (const float4*)(kv + b * 4096);
  float4* d4 = (float4*)&KVs[0][0];
#pragma unroll
  for (int i = 0; i < 4; i++) d4[i * 256 + t] = s4[i * 256 + t];

  const float* qp = qq + gr * 64 + h * 8;
  float4 qa = *(const float4*)qp, qb = *(const float4*)(qp + 4);
  __syncthreads();

  {
    float num[8] = {0.f, 0.f, 0.f, 0.f, 0.f, 0.f, 0.f, 0.f};
    float den = 0.f;
#pragma unroll
    for (int jj = 0; jj < 4; jj++) {
      int j = jj * 8 + g;
      float4 ka = *(const float4*)&KVs[j][h * 8];
      float4 kb = *(const float4*)&KVs[j][h * 8 + 4];
      float s = qa.x * ka.x + qa.y * ka.y + qa.z * ka.z + qa.w * ka.w +
                qb.x * kb.x + qb.y * kb.y + qb.z * kb.z + qb.w * kb.w;
      s *= ATT_SCALE;
      s = fminf(fmaxf(s, -5.f), 5.f);
      float ex = __expf(s);
      den += ex;
      float4 va = *(const float4*)&KVs[j][64 + h * 8];
      float4 vb = *(const float4*)&KVs[j][64 + h * 8 + 4];
      num[0] += ex * va.x; num[1] += ex * va.y;
      num[2] += ex * va.z; num[3] += ex * va.w;
      num[4] += ex * vb.x; num[5] += ex * vb.y;
      num[6] += ex * vb.z; num[7] += ex * vb.w;
    }
    den += __shfl_xor(den, 1); den += __shfl_xor(den, 2); den += __shfl_xor(den, 4);
#pragma unroll
    for (int d = 0; d < 8; d++) {
      float v = num[d];
      v += __shfl_xor(v, 1); v += __shfl_xor(v, 2); v += __shfl_xor(v, 4);
      num[d] = v;
    }
    float sel = num[0];
#pragma unroll
    for (int d = 1; d < 8; d++) sel = (g == d) ? num[d] : sel;
    ocs[rr][h * 8 + g] = sel / den;
  }

  int c = l;
  {
    float acc = resid[gr * 64 + c] + bo[c];
    for (int k = 0; k < 64; k++) acc += ocs[rr][k] * wo[k * 64 + c];
    q_out[gr * 64 + c] = acc;
    q2s[rr][c] = acc;
  }
  {
    float aq = 0.f, ak = 0.f, av = 0.f;
    for (int k = 0; k < 64; k++) {
      float x = q2s[rr][k];
      aq += x * wq2[k * 64 + c];
      ak += x * wkv2[k * 128 + c];
      av += x * wkv2[k * 128 + 64 + c];
    }
    qq2[gr * 64 + c] = aq;
    kv2[gr * 128 + c] = ak;
    kv2[gr * 128 + 64 + c] = av;
  }
}

// ---------------------------------------------------------------------------
// KC: latent self-attn layer 1 + q2 residual + oq_w + LN1 + FFN + LN2 -> out
// grid 64 x 256, one barrier.
// ---------------------------------------------------------------------------
__global__ __launch_bounds__(256) void k_finalf(
    const float* __restrict__ qq, const float* __restrict__ kv,
    const float* __restrict__ resid, const float* __restrict__ wo,
    const float* __restrict__ bo, const float* __restrict__ oqw,
    const float* __restrict__ g1, const float* __restrict__ b1,
    const float* __restrict__ w1, const float* __restrict__ w2,
    const float* __restrict__ g2, const float* __restrict__ b2v,
    float* __restrict__ out) {
  int blk = blockIdx.x, b = blk >> 3, rg = blk & 7;
  int t = threadIdx.x, rr = t >> 6, l = t & 63, h = l >> 3, g = l & 7;
  int gr = b * 32 + rg * 4 + rr;
  __shared__ float KVs[32][128];
  __shared__ float ocs[4][64];
  __shared__ float xs[4][64];
  __shared__ float hs[4][128];

  const float4* s4 = (const float4*)(kv + b * 4096);
  float4* d4 = (float4*)&KVs[0][0];
#pragma unroll
  for (int i = 0; i < 4; i++) d4[i * 256 + t] = s4[i * 256 + t];

  const float* qp = qq + gr * 64 + h * 8;
  float4 qa = *(const float4*)qp, qb = *(const float4*)(qp + 4);
  __syncthreads();

  {
    float num[8] = {0.f, 0.f, 0.f, 0.f, 0.f, 0.f, 0.f, 0.f};
    float den = 0.f;
#pragma unroll
    for (int jj = 0; jj < 4; jj++) {
      int j = jj * 8 + g;
      float4 ka = *(const float4*)&KVs[j][h * 8];
      float4 kb = *(const float4*)&KVs[j][h * 8 + 4];
      float s = qa.x * ka.x + qa.y * ka.y + qa.z * ka.z + qa.w * ka.w +
                qb.x * kb.x + qb.y * kb.y + qb.z * kb.z + qb.w * kb.w;
      s *= ATT_SCALE;
      s = fminf(fmaxf(s, -5.f), 5.f);
      float ex = __expf(s);
      den += ex;
      float4 va = *(const float4*)&KVs[j][64 + h * 8];
      float4 vb = *(const float4*)&KVs[j][64 + h * 8 + 4];
      num[0] += ex * va.x; num[1] += ex * va.y;
      num[2] += ex * va.z; num[3] += ex * va.w;
      num[4] += ex * vb.x; num[5] += ex * vb.y;
      num[6] += ex * vb.z; num[7] += ex * vb.w;
    }
    den += __shfl_xor(den, 1); den += __shfl_xor(den, 2); den += __shfl_xor(den, 4);
#pragma unroll
    for (int d = 0; d < 8; d++) {
      float v = num[d];
      v += __shfl_xor(v, 1); v += __shfl_xor(v, 2); v += __shfl_xor(v, 4);
      num[d] = v;
    }
    float sel = num[0];
#pragma unroll
    for (int d = 1; d < 8; d++) sel = (g == d) ? num[d] : sel;
    ocs[rr][h * 8 + g] = sel / den;
  }

  int c = l;
  float y;
  {
    float acc = resid[gr * 64 + c] + bo[c];
    for (int k = 0; k < 64; k++) acc += ocs[rr][k] * wo[k * 64 + c];
    xs[rr][c] = acc;   // q2 (row-local)
  }
  {
    float x = 0.f;
    for (int k = 0; k < 64; k++) x += xs[rr][k] * oqw[k * 64 + c];
    float m = x;
    for (int off = 1; off < 64; off <<= 1) m += __shfl_xor(m, off);
    m *= (1.f / 64.f);
    float dv = x - m, vv = dv * dv;
    for (int off = 1; off < 64; off <<= 1) vv += __shfl_xor(vv, off);
    vv *= (1.f / 64.f);
    y = dv * rsqrtf(vv + 1e-5f) * g1[c] + b1[c];
    xs[rr][c] = y;     // reuse: this wave done reading q2
  }
  {
    float h1 = 0.f, h2 = 0.f;
    for (int k = 0; k < 64; k++) {
      float xx = xs[rr][k];
      h1 += xx * w1[k * 128 + c];
      h2 += xx * w1[k * 128 + 64 + c];
    }
    hs[rr][c] = fmaxf(h1, 0.f);
    hs[rr][64 + c] = fmaxf(h2, 0.f);
  }
  {
    float ff = 0.f;
    for (int k = 0; k < 128; k++) ff += hs[rr][k] * w2[k * 64 + c];
    float z = y + ff;
    float m2 = z;
    for (int off = 1; off < 64; off <<= 1) m2 += __shfl_xor(m2, off);
    m2 *= (1.f / 64.f);
    float dz = z - m2, v2 = dz * dz;
    for (int off = 1; off < 64; off <<= 1) v2 += __shfl_xor(v2, off);
    v2 *= (1.f / 64.f);
    out[gr * 64 + c] = dz * rsqrtf(v2 + 1e-5f) * g2[c] + b2v[c];
  }
}

// ---------------------------------------------------------------------------
extern "C" void kernel_launch(void* const* d_in, const int* in_sizes, int n_in,
                              void* d_out, int out_size, void* d_ws, size_t ws_size,
                              hipStream_t stream) {
  const float* h_in   = (const float*)d_in[0];
  const float* p_in   = (const float*)d_in[1];
  const float* e_in   = (const float*)d_in[2];
  const float* krw    = (const float*)d_in[3];
  const float* quer   = (const float*)d_in[4];
  const float* mask   = (const float*)d_in[5];
  const float* wq_p   = (const float*)d_in[6];
  const float* wk_p   = (const float*)d_in[7];
  const float* we_p   = (const float*)d_in[8];
  const float* wv_p   = (const float*)d_in[9];
  const float* wo_p   = (const float*)d_in[10];
  const float* cq_wq  = (const float*)d_in[11];
  const float* cq_wkv = (const float*)d_in[12];
  const float* cq_wo  = (const float*)d_in[13];
  const float* cq_bo  = (const float*)d_in[14];
  const float* sa_wq  = (const float*)d_in[15];
  const float* sa_wkv = (const float*)d_in[16];
  const float* sa_wo  = (const float*)d_in[17];
  const float* sa_bo  = (const float*)d_in[18];
  const float* oq_w   = (const float*)d_in[19];
  const float* ln1_g  = (const float*)d_in[20];
  const float* ln1_b  = (const float*)d_in[21];
  const float* ffn_w1 = (const float*)d_in[22];
  const float* ffn_w2 = (const float*)d_in[23];
  const float* ln2_g  = (const float*)d_in[24];
  const float* ln2_b  = (const float*)d_in[25];

  float* ws = (float*)d_ws;
  float* Q   = ws;              // 131072
  float* Ks  = Q + 131072;      // 131072
  float* V   = Ks + 131072;     // 131072
  float* q1  = V + 131072;      // 16384
  float* Kc  = q1 + 16384;      // 131072
  float* Vc  = Kc + 131072;     // 131072
  float* q0  = Vc + 131072;     // 16384
  float* qc1 = q0 + 16384;      // 16384
  float* qqA = qc1 + 16384;     // 16384
  float* qqB = qqA + 16384;     // 16384
  float* kvA = qqB + 16384;     // 32768
  float* kvB = kvA + 32768;     // 32768

  k_proj<<<2304, 64, 0, stream>>>(p_in, quer, wq_p, wk_p, wv_p, cq_wq, Q, Ks, V, q1);
  k_edge<<<2048, 256, 0, stream>>>(e_in, we_p, krw, mask, h_in, p_in, wo_p, cq_wkv,
                                   Q, Ks, V, Kc, Vc);
  k_crossf<<<64, 256, 0, stream>>>(q1, Kc, Vc, mask, quer, cq_wo, cq_bo,
                                   sa_wq, sa_wkv, q0, qqA, kvA);
  k_sattnf<<<64, 256, 0, stream>>>(qqA, kvA, q0, sa_wo, sa_bo,
                                   sa_wq + 4096, sa_wkv + 8192, qc1, qqB, kvB);
  k_finalf<<<64, 256, 0, stream>>>(qqB, kvB, qc1, sa_wo + 4096, sa_bo + 64, oq_w,
                                   ln1_g, ln1_b, ffn_w1, ffn_w2, ln2_g, ln2_b,
                                   (float*)d_out);
}

// Round 5
// 329.298 us; speedup vs baseline: 1.0194x; 1.0194x over previous
//
#include <hip/hip_runtime.h>
#include <hip/hip_bf16.h>
#include <math.h>

typedef __bf16 bf16x8 __attribute__((ext_vector_type(8)));
typedef float floatx4 __attribute__((ext_vector_type(4)));

#define ATT_SCALE 0.35355339059327373f  // DH^-0.5, DH=8

__device__ __forceinline__ __bf16 f2b(float x) { return (__bf16)x; }

// ---------------------------------------------------------------------------
// K1: Q = p@wq, Ks = (p@wk)*SCALE, V = p@wv  (rows 0..2047), q1 = queries@cq_wq
// grid 2304 x 64
// ---------------------------------------------------------------------------
__global__ void k_proj(const float* __restrict__ p, const float* __restrict__ quer,
                       const float* __restrict__ wq, const float* __restrict__ wk,
                       const float* __restrict__ wv, const float* __restrict__ cq_wq,
                       float* __restrict__ Q, float* __restrict__ Ks,
                       float* __restrict__ V, float* __restrict__ q1) {
  int blk = blockIdx.x, t = threadIdx.x;
  __shared__ float xr[64];
  if (blk < 2048) {
    xr[t] = p[blk * 64 + t];
    __syncthreads();
    float aq = 0.f, ak = 0.f, av = 0.f;
    for (int c = 0; c < 64; c++) {
      float x = xr[c];
      aq += x * wq[c * 64 + t];
      ak += x * wk[c * 64 + t];
      av += x * wv[c * 64 + t];
    }
    Q[blk * 64 + t] = aq;
    Ks[blk * 64 + t] = ak * ATT_SCALE;
    V[blk * 64 + t] = av;
  } else {
    int r = blk - 2048;  // 0..255 query rows
    xr[t] = quer[r * 64 + t];
    __syncthreads();
    float a = 0.f;
    for (int c = 0; c < 64; c++) a += xr[c] * cq_wq[c * 64 + t];
    q1[r * 64 + t] = a;
  }
}

// ---------------------------------------------------------------------------
// K2 v6: edge attention, transposed MFMA, all-tiles-early e prefetch, correct
// vmcnt age ordering. __launch_bounds__(256,1) lifts the VGPR cap to 256 so
// nothing spills (rounds 3/4: default 1024-thread assumption capped VGPRs at
// 64 and scratch-spilled 48 MB).
// grid 2048 x 256 (wave w owns j in [w*64, w*64+64))
// ---------------------------------------------------------------------------
#define LOADT(ER, JT) do {                         \
    const float* _np = ebase + (JT) * 1024;        \
    ER[0] = *(const float4*)(_np);                 \
    ER[1] = *(const float4*)(_np + 4);             \
    ER[2] = *(const float4*)(_np + 32);            \
    ER[3] = *(const float4*)(_np + 36);            \
  } while (0)

#define NTCOMP(NT, KF, VA) do {                                               \
    floatx4 acc = {0.f, 0.f, 0.f, 0.f};                                       \
    acc = __builtin_amdgcn_mfma_f32_16x16x32_bf16(wfrag[NT][0], a0, acc, 0, 0, 0); \
    acc = __builtin_amdgcn_mfma_f32_16x16x32_bf16(wfrag[NT][1], a1, acc, 0, 0, 0); \
    float s = acc[0] * KF.x * qv[NT].x + acc[1] * KF.y * qv[NT].y +           \
              acc[2] * KF.z * qv[NT].z + acc[3] * KF.w * qv[NT].w;            \
    s += __shfl_xor(s, 16);                                                   \
    float wg = __expf(s) * kwm;                                               \
    aden[NT] += wg;                                                           \
    aout[NT][0] += wg * VA.x; aout[NT][1] += wg * VA.y;                       \
    aout[NT][2] += wg * VA.z; aout[NT][3] += wg * VA.w;                       \
  } while (0)

#define STEP(JT, ER, PFSTMT) do {                                             \
    int jS = w * 64 + (JT) * 16 + l15;                                        \
    const float* ksrow = Ks + ((long)(b * 256 + jS)) * 64 + quad * 4;         \
    const float* vrow  = V  + ((long)(b * 256 + jS)) * 64 + hsel * 8 + par * 4; \
    float4 kf0 = *(const float4*)(ksrow);                                     \
    float4 kf1 = *(const float4*)(ksrow + 16);                                \
    float4 kf2 = *(const float4*)(ksrow + 32);                                \
    float4 kf3 = *(const float4*)(ksrow + 48);                                \
    float4 va0 = *(const float4*)(vrow);                                      \
    float4 va1 = *(const float4*)(vrow + 16);                                 \
    float4 va2 = *(const float4*)(vrow + 32);                                 \
    float4 va3 = *(const float4*)(vrow + 48);                                 \
    float kwm = krw[(long)bi * 256 + jS] * mask[b * 256 + jS];                \
    __builtin_amdgcn_sched_barrier(0);                                        \
    PFSTMT;                                                                   \
    __builtin_amdgcn_sched_barrier(0);                                        \
    bf16x8 a0, a1;                                                            \
    a0[0] = f2b(ER[0].x); a0[1] = f2b(ER[0].y);                               \
    a0[2] = f2b(ER[0].z); a0[3] = f2b(ER[0].w);                               \
    a0[4] = f2b(ER[1].x); a0[5] = f2b(ER[1].y);                               \
    a0[6] = f2b(ER[1].z); a0[7] = f2b(ER[1].w);                               \
    a1[0] = f2b(ER[2].x); a1[1] = f2b(ER[2].y);                               \
    a1[2] = f2b(ER[2].z); a1[3] = f2b(ER[2].w);                               \
    a1[4] = f2b(ER[3].x); a1[5] = f2b(ER[3].y);                               \
    a1[6] = f2b(ER[3].z); a1[7] = f2b(ER[3].w);                               \
    NTCOMP(0, kf0, va0); NTCOMP(1, kf1, va1);                                 \
    NTCOMP(2, kf2, va2); NTCOMP(3, kf3, va3);                                 \
  } while (0)

__global__ __launch_bounds__(256, 1) void k_edge(
    const float* __restrict__ e, const float* __restrict__ we,
    const float* __restrict__ krw, const float* __restrict__ mask,
    const float* __restrict__ hin, const float* __restrict__ pin,
    const float* __restrict__ wo, const float* __restrict__ cq_wkv,
    const float* __restrict__ Q, const float* __restrict__ Ks,
    const float* __restrict__ V, float* __restrict__ Kc, float* __restrict__ Vc) {
  int bi = blockIdx.x;          // b*256 + i
  int b = bi >> 8;
  int t = threadIdx.x;
  int w = t >> 6, l = t & 63;
  int l15 = l & 15, quad = l >> 4;
  int hsel = quad >> 1;         // head offset within an nt pair (0 or 1)
  int par = quad & 1;           // dim-half this lane accumulates

  // we fragments (L2): lane holds we[c=kc*32+quad*8+jj][hk=nt*16+l15]
  bf16x8 wfrag[4][2];
#pragma unroll
  for (int nt = 0; nt < 4; nt++)
#pragma unroll
    for (int kc = 0; kc < 2; kc++)
#pragma unroll
      for (int jj = 0; jj < 8; jj++)
        wfrag[nt][kc][jj] = f2b(we[(kc * 32 + quad * 8 + jj) * 64 + nt * 16 + l15]);

  // qv is loop-invariant: Q[i][nt*16 + quad*4 .. +3]
  float4 qv[4];
#pragma unroll
  for (int nt = 0; nt < 4; nt++)
    qv[nt] = *(const float4*)(Q + bi * 64 + nt * 16 + quad * 4);

  float mi = mask[bi];

  float aout[4][4];
  float aden[4] = {0.f, 0.f, 0.f, 0.f};
#pragma unroll
  for (int nt = 0; nt < 4; nt++)
#pragma unroll
    for (int d = 0; d < 4; d++) aout[nt][d] = 0.f;

  const float* ebase = e + ((long)bi * 256 + w * 64 + l15) * 64 + quad * 8;

  float4 e0[4], e1[4], e2[4], e3[4];
  LOADT(e0, 0);
  LOADT(e1, 1);
  LOADT(e2, 2);
  __builtin_amdgcn_sched_barrier(0);

  STEP(0, e0, LOADT(e3, 3));
  STEP(1, e1, (void)0);
  STEP(2, e2, (void)0);
  STEP(3, e3, (void)0);

  // reduce over the 16 j's per lane-group (l15)
#pragma unroll
  for (int nt = 0; nt < 4; nt++) {
    float dn = aden[nt];
    dn += __shfl_xor(dn, 1); dn += __shfl_xor(dn, 2);
    dn += __shfl_xor(dn, 4); dn += __shfl_xor(dn, 8);
    aden[nt] = dn;
#pragma unroll
    for (int d = 0; d < 4; d++) {
      float o = aout[nt][d];
      o += __shfl_xor(o, 1); o += __shfl_xor(o, 2);
      o += __shfl_xor(o, 4); o += __shfl_xor(o, 8);
      aout[nt][d] = o;
    }
  }

  __shared__ float red[4][64];
  __shared__ float redden[4][8];
  __shared__ float pav[64];
  __shared__ float hcl[64];
  if (l15 == 0) {               // lanes 0,16,32,48 of each wave
#pragma unroll
    for (int nt = 0; nt < 4; nt++) {
      int head = nt * 2 + hsel;
#pragma unroll
      for (int d = 0; d < 4; d++) red[w][head * 8 + par * 4 + d] = aout[nt][d];
      if (par == 0) redden[w][head] = aden[nt];
    }
  }
  __syncthreads();
  if (t < 64) {
    int head = t >> 3;
    float num = red[0][t] + red[1][t] + red[2][t] + red[3][t];
    float den = redden[0][head] + redden[1][head] + redden[2][head] + redden[3][head];
    num *= mi;
    den = fmaxf(den * mi, 1e-6f);
    pav[t] = num / den;  // p_attn[b,i,head*8+d]
  }
  __syncthreads();
  if (t < 64) {
    float a = 0.f;
    for (int c = 0; c < 64; c++) a += pav[c] * wo[c * 64 + t];
    hcl[t] = hin[bi * 64 + t] + pin[bi * 64 + t] + tanhf(a);
  }
  __syncthreads();
  if (t < 128) {
    float a = 0.f;
    for (int c = 0; c < 64; c++) a += hcl[c] * cq_wkv[c * 128 + t];
    if (t < 64) Kc[bi * 64 + t] = a;
    else        Vc[bi * 64 + t - 64] = a;
  }
}

// ---------------------------------------------------------------------------
// KA: cross-attn (4 latent rows per block, all heads) + q0 = quer + oc@cq_wo
//     + bo, then qq/kv projections for self-attn layer 0.
// grid 64 (b*8+rg) x 256. Row-local LDS only -> no barriers needed.
// ---------------------------------------------------------------------------
__global__ __launch_bounds__(256) void k_crossf(
    const float* __restrict__ q1, const float* __restrict__ Kc,
    const float* __restrict__ Vc, const float* __restrict__ mask,
    const float* __restrict__ quer, const float* __restrict__ cq_wo,
    const float* __restrict__ cq_bo, const float* __restrict__ wq0,
    const float* __restrict__ wkv0, float* __restrict__ q0g,
    float* __restrict__ qqg, float* __restrict__ kvg) {
  int blk = blockIdx.x, b = blk >> 3, rg = blk & 7;
  int t = threadIdx.x, rr = t >> 6, l = t & 63, h = l >> 3, g = l & 7;
  int gr = b * 32 + rg * 4 + rr;  // global latent row
  __shared__ float ocs[4][64];
  __shared__ float q0s[4][64];

  {
    const float* qp = q1 + gr * 64 + h * 8;
    float4 qa = *(const float4*)qp, qb = *(const float4*)(qp + 4);
    float num[8] = {0.f, 0.f, 0.f, 0.f, 0.f, 0.f, 0.f, 0.f};
    float den = 0.f;
#pragma unroll 4
    for (int jj = 0; jj < 32; jj++) {
      int j = jj * 8 + g;
      const float* kp = Kc + (b * 256 + j) * 64 + h * 8;
      float4 ka = *(const float4*)kp, kb = *(const float4*)(kp + 4);
      float s = qa.x * ka.x + qa.y * ka.y + qa.z * ka.z + qa.w * ka.w +
                qb.x * kb.x + qb.y * kb.y + qb.z * kb.z + qb.w * kb.w;
      s *= ATT_SCALE;
      float mj = mask[b * 256 + j];
      s = (mj > 0.5f) ? s : -1e30f;
      s = fminf(fmaxf(s, -5.f), 5.f);
      float ex = __expf(s);
      den += ex;
      const float* vp = Vc + (b * 256 + j) * 64 + h * 8;
      float4 va = *(const float4*)vp, vb = *(const float4*)(vp + 4);
      num[0] += ex * va.x; num[1] += ex * va.y;
      num[2] += ex * va.z; num[3] += ex * va.w;
      num[4] += ex * vb.x; num[5] += ex * vb.y;
      num[6] += ex * vb.z; num[7] += ex * vb.w;
    }
    den += __shfl_xor(den, 1); den += __shfl_xor(den, 2); den += __shfl_xor(den, 4);
#pragma unroll
    for (int d = 0; d < 8; d++) {
      float v = num[d];
      v += __shfl_xor(v, 1); v += __shfl_xor(v, 2); v += __shfl_xor(v, 4);
      num[d] = v;
    }
    float sel = num[0];
#pragma unroll
    for (int d = 1; d < 8; d++) sel = (g == d) ? num[d] : sel;
    ocs[rr][h * 8 + g] = sel / den;   // row-local: read only by this wave
  }

  int c = l;
  {
    float acc = quer[gr * 64 + c] + cq_bo[c];
    for (int k = 0; k < 64; k++) acc += ocs[rr][k] * cq_wo[k * 64 + c];
    q0g[gr * 64 + c] = acc;
    q0s[rr][c] = acc;
  }
  {
    float aq = 0.f, ak = 0.f, av = 0.f;
    for (int k = 0; k < 64; k++) {
      float x = q0s[rr][k];
      aq += x * wq0[k * 64 + c];
      ak += x * wkv0[k * 128 + c];
      av += x * wkv0[k * 128 + 64 + c];
    }
    qqg[gr * 64 + c] = aq;
    kvg[gr * 128 + c] = ak;
    kvg[gr * 128 + 64 + c] = av;
  }
}

// ---------------------------------------------------------------------------
// KB: latent self-attn (4 rows per block, K/V staged in LDS) + residual
//     projection + next layer's qq/kv projections.
// grid 64 x 256, one barrier (after K/V stage).
// ---------------------------------------------------------------------------
__global__ __launch_bounds__(256) void k_sattnf(
    const float* __restrict__ qq, const float* __restrict__ kv,
    const float* __restrict__ resid, const float* __restrict__ wo,
    const float* __restrict__ bo, const float* __restrict__ wq2,
    const float* __restrict__ wkv2, float* __restrict__ q_out,
    float* __restrict__ qq2, float* __restrict__ kv2) {
  int blk = blockIdx.x, b = blk >> 3, rg = blk & 7;
  int t = threadIdx.x, rr = t >> 6, l = t & 63, h = l >> 3, g = l & 7;
  int gr = b * 32 + rg * 4 + rr;
  __shared__ float KVs[32][128];
  __shared__ float ocs[4][64];
  __shared__ float q2s[4][64];

  const float4* s4 = (const float4*)(kv + b * 4096);
  float4* d4 = (float4*)&KVs[0][0];
#pragma unroll
  for (int i = 0; i < 4; i++) d4[i * 256 + t] = s4[i * 256 + t];

  const float* qp = qq + gr * 64 + h * 8;
  float4 qa = *(const float4*)qp, qb = *(const float4*)(qp + 4);
  __syncthreads();

  {
    float num[8] = {0.f, 0.f, 0.f, 0.f, 0.f, 0.f, 0.f, 0.f};
    float den = 0.f;
#pragma unroll
    for (int jj = 0; jj < 4; jj++) {
      int j = jj * 8 + g;
      float4 ka = *(const float4*)&KVs[j][h * 8];
      float4 kb = *(const float4*)&KVs[j][h * 8 + 4];
      float s = qa.x * ka.x + qa.y * ka.y + qa.z * ka.z + qa.w * ka.w +
                qb.x * kb.x + qb.y * kb.y + qb.z * kb.z + qb.w * kb.w;
      s *= ATT_SCALE;
      s = fminf(fmaxf(s, -5.f), 5.f);
      float ex = __expf(s);
      den += ex;
      float4 va = *(const float4*)&KVs[j][64 + h * 8];
      float4 vb = *(const float4*)&KVs[j][64 + h * 8 + 4];
      num[0] += ex * va.x; num[1] += ex * va.y;
      num[2] += ex * va.z; num[3] += ex * va.w;
      num[4] += ex * vb.x; num[5] += ex * vb.y;
      num[6] += ex * vb.z; num[7] += ex * vb.w;
    }
    den += __shfl_xor(den, 1); den += __shfl_xor(den, 2); den += __shfl_xor(den, 4);
#pragma unroll
    for (int d = 0; d < 8; d++) {
      float v = num[d];
      v += __shfl_xor(v, 1); v += __shfl_xor(v, 2); v += __shfl_xor(v, 4);
      num[d] = v;
    }
    float sel = num[0];
#pragma unroll
    for (int d = 1; d < 8; d++) sel = (g == d) ? num[d] : sel;
    ocs[rr][h * 8 + g] = sel / den;
  }

  int c = l;
  {
    float acc = resid[gr * 64 + c] + bo[c];
    for (int k = 0; k < 64; k++) acc += ocs[rr][k] * wo[k * 64 + c];
    q_out[gr * 64 + c] = acc;
    q2s[rr][c] = acc;
  }
  {
    float aq = 0.f, ak = 0.f, av = 0.f;
    for (int k = 0; k < 64; k++) {
      float x = q2s[rr][k];
      aq += x * wq2[k * 64 + c];
      ak += x * wkv2[k * 128 + c];
      av += x * wkv2[k * 128 + 64 + c];
    }
    qq2[gr * 64 + c] = aq;
    kv2[gr * 128 + c] = ak;
    kv2[gr * 128 + 64 + c] = av;
  }
}

// ---------------------------------------------------------------------------
// KC: latent self-attn layer 1 + q2 residual + oq_w + LN1 + FFN + LN2 -> out
// grid 64 x 256, one barrier.
// ---------------------------------------------------------------------------
__global__ __launch_bounds__(256) void k_finalf(
    const float* __restrict__ qq, const float* __restrict__ kv,
    const float* __restrict__ resid, const float* __restrict__ wo,
    const float* __restrict__ bo, const float* __restrict__ oqw,
    const float* __restrict__ g1, const float* __restrict__ b1,
    const float* __restrict__ w1, const float* __restrict__ w2,
    const float* __restrict__ g2, const float* __restrict__ b2v,
    float* __restrict__ out) {
  int blk = blockIdx.x, b = blk >> 3, rg = blk & 7;
  int t = threadIdx.x, rr = t >> 6, l = t & 63, h = l >> 3, g = l & 7;
  int gr = b * 32 + rg * 4 + rr;
  __shared__ float KVs[32][128];
  __shared__ float ocs[4][64];
  __shared__ float xs[4][64];
  __shared__ float hs[4][128];

  const float4* s4 = (const float4*)(kv + b * 4096);
  float4* d4 = (float4*)&KVs[0][0];
#pragma unroll
  for (int i = 0; i < 4; i++) d4[i * 256 + t] = s4[i * 256 + t];

  const float* qp = qq + gr * 64 + h * 8;
  float4 qa = *(const float4*)qp, qb = *(const float4*)(qp + 4);
  __syncthreads();

  {
    float num[8] = {0.f, 0.f, 0.f, 0.f, 0.f, 0.f, 0.f, 0.f};
    float den = 0.f;
#pragma unroll
    for (int jj = 0; jj < 4; jj++) {
      int j = jj * 8 + g;
      float4 ka = *(const float4*)&KVs[j][h * 8];
      float4 kb = *(const float4*)&KVs[j][h * 8 + 4];
      float s = qa.x * ka.x + qa.y * ka.y + qa.z * ka.z + qa.w * ka.w +
                qb.x * kb.x + qb.y * kb.y + qb.z * kb.z + qb.w * kb.w;
      s *= ATT_SCALE;
      s = fminf(fmaxf(s, -5.f), 5.f);
      float ex = __expf(s);
      den += ex;
      float4 va = *(const float4*)&KVs[j][64 + h * 8];
      float4 vb = *(const float4*)&KVs[j][64 + h * 8 + 4];
      num[0] += ex * va.x; num[1] += ex * va.y;
      num[2] += ex * va.z; num[3] += ex * va.w;
      num[4] += ex * vb.x; num[5] += ex * vb.y;
      num[6] += ex * vb.z; num[7] += ex * vb.w;
    }
    den += __shfl_xor(den, 1); den += __shfl_xor(den, 2); den += __shfl_xor(den, 4);
#pragma unroll
    for (int d = 0; d < 8; d++) {
      float v = num[d];
      v += __shfl_xor(v, 1); v += __shfl_xor(v, 2); v += __shfl_xor(v, 4);
      num[d] = v;
    }
    float sel = num[0];
#pragma unroll
    for (int d = 1; d < 8; d++) sel = (g == d) ? num[d] : sel;
    ocs[rr][h * 8 + g] = sel / den;
  }

  int c = l;
  float y;
  {
    float acc = resid[gr * 64 + c] + bo[c];
    for (int k = 0; k < 64; k++) acc += ocs[rr][k] * wo[k * 64 + c];
    xs[rr][c] = acc;   // q2 (row-local)
  }
  {
    float x = 0.f;
    for (int k = 0; k < 64; k++) x += xs[rr][k] * oqw[k * 64 + c];
    float m = x;
    for (int off = 1; off < 64; off <<= 1) m += __shfl_xor(m, off);
    m *= (1.f / 64.f);
    float dv = x - m, vv = dv * dv;
    for (int off = 1; off < 64; off <<= 1) vv += __shfl_xor(vv, off);
    vv *= (1.f / 64.f);
    y = dv * rsqrtf(vv + 1e-5f) * g1[c] + b1[c];
    xs[rr][c] = y;     // reuse: this wave done reading q2
  }
  {
    float h1 = 0.f, h2 = 0.f;
    for (int k = 0; k < 64; k++) {
      float xx = xs[rr][k];
      h1 += xx * w1[k * 128 + c];
      h2 += xx * w1[k * 128 + 64 + c];
    }
    hs[rr][c] = fmaxf(h1, 0.f);
    hs[rr][64 + c] = fmaxf(h2, 0.f);
  }
  {
    float ff = 0.f;
    for (int k = 0; k < 128; k++) ff += hs[rr][k] * w2[k * 64 + c];
    float z = y + ff;
    float m2 = z;
    for (int off = 1; off < 64; off <<= 1) m2 += __shfl_xor(m2, off);
    m2 *= (1.f / 64.f);
    float dz = z - m2, v2 = dz * dz;
    for (int off = 1; off < 64; off <<= 1) v2 += __shfl_xor(v2, off);
    v2 *= (1.f / 64.f);
    out[gr * 64 + c] = dz * rsqrtf(v2 + 1e-5f) * g2[c] + b2v[c];
  }
}

// ---------------------------------------------------------------------------
extern "C" void kernel_launch(void* const* d_in, const int* in_sizes, int n_in,
                              void* d_out, int out_size, void* d_ws, size_t ws_size,
                              hipStream_t stream) {
  const float* h_in   = (const float*)d_in[0];
  const float* p_in   = (const float*)d_in[1];
  const float* e_in   = (const float*)d_in[2];
  const float* krw    = (const float*)d_in[3];
  const float* quer   = (const float*)d_in[4];
  const float* mask   = (const float*)d_in[5];
  const float* wq_p   = (const float*)d_in[6];
  const float* wk_p   = (const float*)d_in[7];
  const float* we_p   = (const float*)d_in[8];
  const float* wv_p   = (const float*)d_in[9];
  const float* wo_p   = (const float*)d_in[10];
  const float* cq_wq  = (const float*)d_in[11];
  const float* cq_wkv = (const float*)d_in[12];
  const float* cq_wo  = (const float*)d_in[13];
  const float* cq_bo  = (const float*)d_in[14];
  const float* sa_wq  = (const float*)d_in[15];
  const float* sa_wkv = (const float*)d_in[16];
  const float* sa_wo  = (const float*)d_in[17];
  const float* sa_bo  = (const float*)d_in[18];
  const float* oq_w   = (const float*)d_in[19];
  const float* ln1_g  = (const float*)d_in[20];
  const float* ln1_b  = (const float*)d_in[21];
  const float* ffn_w1 = (const float*)d_in[22];
  const float* ffn_w2 = (const float*)d_in[23];
  const float* ln2_g  = (const float*)d_in[24];
  const float* ln2_b  = (const float*)d_in[25];

  float* ws = (float*)d_ws;
  float* Q   = ws;              // 131072
  float* Ks  = Q + 131072;      // 131072
  float* V   = Ks + 131072;     // 131072
  float* q1  = V + 131072;      // 16384
  float* Kc  = q1 + 16384;      // 131072
  float* Vc  = Kc + 131072;     // 131072
  float* q0  = Vc + 131072;     // 16384
  float* qc1 = q0 + 16384;      // 16384
  float* qqA = qc1 + 16384;     // 16384
  float* qqB = qqA + 16384;     // 16384
  float* kvA = qqB + 16384;     // 32768
  float* kvB = kvA + 32768;     // 32768

  k_proj<<<2304, 64, 0, stream>>>(p_in, quer, wq_p, wk_p, wv_p, cq_wq, Q, Ks, V, q1);
  k_edge<<<2048, 256, 0, stream>>>(e_in, we_p, krw, mask, h_in, p_in, wo_p, cq_wkv,
                                   Q, Ks, V, Kc, Vc);
  k_crossf<<<64, 256, 0, stream>>>(q1, Kc, Vc, mask, quer, cq_wo, cq_bo,
                                   sa_wq, sa_wkv, q0, qqA, kvA);
  k_sattnf<<<64, 256, 0, stream>>>(qqA, kvA, q0, sa_wo, sa_bo,
                                   sa_wq + 4096, sa_wkv + 8192, qc1, qqB, kvB);
  k_finalf<<<64, 256, 0, stream>>>(qqB, kvB, qc1, sa_wo + 4096, sa_bo + 64, oq_w,
                                   ln1_g, ln1_b, ffn_w1, ffn_w2, ln2_g, ln2_b,
                                   (float*)d_out);
}